// Round 4
// baseline (159.258 us; speedup 1.0000x reference)
//
#include <hip/hip_runtime.h>
#include <hip/hip_bf16.h>
#include <stdint.h>

#define N_NODES 10000
#define N_EDGES 320000
#define DD 256

typedef __attribute__((ext_vector_type(4))) float f32x4;
typedef __attribute__((ext_vector_type(8))) short short8;
typedef __attribute__((ext_vector_type(4))) short short4v;

__device__ __forceinline__ short f2b(float f) {
  unsigned u = __builtin_bit_cast(unsigned, f);
  u += 0x7fffu + ((u >> 16) & 1u);  // round-to-nearest-even
  return (short)(u >> 16);
}
__device__ __forceinline__ float b2f(short s) {
  return __builtin_bit_cast(float, ((unsigned)(unsigned short)s) << 16);
}

// merged: blocks [0,2500) conv_x | [2500,2756) conv_B | [2756,4006) hist
__global__ __launch_bounds__(256) void k_pre(const float* __restrict__ x,
                                             const float* __restrict__ W,
                                             const float* __restrict__ M,
                                             const int* __restrict__ edst,
                                             short* __restrict__ xb,
                                             short* __restrict__ Bb,
                                             int* __restrict__ deg) {
  const int b = blockIdx.x, t = threadIdx.x;
  if (b < 2500) {
    int i = (b * 256 + t) * 4;
    f32x4 v = *(const f32x4*)(x + i);
    short4v o;
    o[0] = f2b(v[0]); o[1] = f2b(v[1]); o[2] = f2b(v[2]); o[3] = f2b(v[3]);
    *(short4v*)(xb + i) = o;
  } else if (b < 2756) {
    int n = b - 2500;  // 0..255
    Bb[n * 512 + t]       = f2b(W[t * DD + n]);
    Bb[n * 512 + t + 256] = f2b(M[t * DD + n]);
  } else {
    int e = (b - 2756) * 256 + t;
    if (e < N_EDGES) atomicAdd(&deg[edst[e]], 1);
  }
}

// exclusive scan of deg[10000] -> rowstart, cursor (single block, 1024 threads x 10)
__global__ __launch_bounds__(1024) void k_scan(const int* __restrict__ deg,
                                               int* __restrict__ rowstart,
                                               int* __restrict__ cursor) {
  __shared__ int wsum[16];
  const int t = threadIdx.x;
  const int base = t * 10;
  int local[10];
  int s = 0;
  #pragma unroll
  for (int i = 0; i < 10; i++) {
    int idx = base + i;
    int dv = (idx < N_NODES) ? deg[idx] : 0;
    local[i] = s;
    s += dv;
  }
  const int lane = t & 63, wv = t >> 6;
  int v = s;
  #pragma unroll
  for (int off = 1; off < 64; off <<= 1) {
    int u = __shfl_up(v, off);
    if (lane >= off) v += u;
  }
  if (lane == 63) wsum[wv] = v;
  __syncthreads();
  if (t < 16) {
    int a = wsum[t];
    int vv = a;
    #pragma unroll
    for (int off = 1; off < 16; off <<= 1) {
      int u = __shfl_up(vv, off);
      if (t >= off) vv += u;
    }
    wsum[t] = vv - a;
  }
  __syncthreads();
  const int excl = (v - s) + wsum[wv];
  #pragma unroll
  for (int i = 0; i < 10; i++) {
    int idx = base + i;
    if (idx < N_NODES) {
      int r = excl + local[i];
      rowstart[idx] = r;
      cursor[idx] = r;
    }
  }
}

__global__ __launch_bounds__(256) void k_scatter(const int* __restrict__ src,
                                                 const int* __restrict__ dst,
                                                 int* __restrict__ cursor,
                                                 int* __restrict__ srcs) {
  int e = blockIdx.x * 256 + threadIdx.x;
  if (e < N_EDGES) {
    int p = atomicAdd(&cursor[dst[e]], 1);
    srcs[p] = src[e];
  }
}

// one wave per node: axb[node] = bf16( sum_{j in N(node)} xb[j] ), f32 accum, MLP-8
__global__ __launch_bounds__(256) void k_agg(const short* __restrict__ xb,
                                             const int* __restrict__ rowstart,
                                             const int* __restrict__ deg,
                                             const int* __restrict__ srcs,
                                             short* __restrict__ axb) {
  const int wave = threadIdx.x >> 6, lane = threadIdx.x & 63;
  const int node = blockIdx.x * 4 + wave;
  const int col = lane * 4;
  float a0 = 0.f, a1 = 0.f, a2 = 0.f, a3 = 0.f;
  const int rs = rowstart[node];
  const int d = deg[node];
  int e = 0;
  for (; e + 8 <= d; e += 8) {
    int s0 = srcs[rs + e],     s1 = srcs[rs + e + 1];
    int s2 = srcs[rs + e + 2], s3 = srcs[rs + e + 3];
    int s4 = srcs[rs + e + 4], s5 = srcs[rs + e + 5];
    int s6 = srcs[rs + e + 6], s7 = srcs[rs + e + 7];
    short4v v0 = *(const short4v*)(xb + s0 * DD + col);
    short4v v1 = *(const short4v*)(xb + s1 * DD + col);
    short4v v2 = *(const short4v*)(xb + s2 * DD + col);
    short4v v3 = *(const short4v*)(xb + s3 * DD + col);
    short4v v4 = *(const short4v*)(xb + s4 * DD + col);
    short4v v5 = *(const short4v*)(xb + s5 * DD + col);
    short4v v6 = *(const short4v*)(xb + s6 * DD + col);
    short4v v7 = *(const short4v*)(xb + s7 * DD + col);
    a0 += b2f(v0[0]) + b2f(v1[0]) + b2f(v2[0]) + b2f(v3[0])
        + b2f(v4[0]) + b2f(v5[0]) + b2f(v6[0]) + b2f(v7[0]);
    a1 += b2f(v0[1]) + b2f(v1[1]) + b2f(v2[1]) + b2f(v3[1])
        + b2f(v4[1]) + b2f(v5[1]) + b2f(v6[1]) + b2f(v7[1]);
    a2 += b2f(v0[2]) + b2f(v1[2]) + b2f(v2[2]) + b2f(v3[2])
        + b2f(v4[2]) + b2f(v5[2]) + b2f(v6[2]) + b2f(v7[2]);
    a3 += b2f(v0[3]) + b2f(v1[3]) + b2f(v2[3]) + b2f(v3[3])
        + b2f(v4[3]) + b2f(v5[3]) + b2f(v6[3]) + b2f(v7[3]);
  }
  for (; e < d; e++) {
    int s = srcs[rs + e];
    short4v v = *(const short4v*)(xb + s * DD + col);
    a0 += b2f(v[0]); a1 += b2f(v[1]); a2 += b2f(v[2]); a3 += b2f(v[3]);
  }
  short4v o;
  o[0] = f2b(a0); o[1] = f2b(a1); o[2] = f2b(a2); o[3] = f2b(a3);
  *(short4v*)(axb + node * DD + col) = o;
}

// out = relu([xb|axb] @ Bb^T): M=10000 (tile 64), N=256 (tile 64), K=512.
// B staged via global_load_lds 16B into row-pair chunks (1024B linear + 16B pad,
// stride 1040B => 2-way banks = free). A fragments direct from global (L2-hot).
// Two phases (K-half 0 from xb, K-half 1 from axb); barrier-free unrolled inner loop.
__global__ __launch_bounds__(256) void k_gemm(const short* __restrict__ xb,
                                              const short* __restrict__ axb,
                                              const short* __restrict__ Bb,
                                              float* __restrict__ out) {
  __shared__ short Bs[32 * 520];  // 32 row-pairs x (1024B data + 16B pad) = 33,280 B
  const int tid = threadIdx.x;
  const int wave = tid >> 6, lane = tid & 63;
  const int m0 = blockIdx.x * 64, n0 = blockIdx.y * 64;
  const int wr = (wave >> 1) * 32, wc = (wave & 1) * 32;
  const int lr = lane & 15, lkb = (lane >> 4) * 8;

  // A rows (clamped; garbage rows only affect masked-out outputs)
  int ar0 = m0 + wr + lr;       if (ar0 > N_NODES - 1) ar0 = N_NODES - 1;
  int ar1 = m0 + wr + 16 + lr;  if (ar1 > N_NODES - 1) ar1 = N_NODES - 1;

  // B LDS element bases for fragment rows wc+lr, wc+16+lr
  const int R0 = wc + lr, R1 = wc + 16 + lr;
  const int bb0 = (R0 >> 1) * 520 + (R0 & 1) * 256 + lkb;
  const int bb1 = (R1 >> 1) * 520 + (R1 & 1) * 256 + lkb;

  f32x4 acc[2][2] = {};

  #pragma unroll
  for (int h = 0; h < 2; h++) {
    const short* __restrict__ Asrc = h ? axb : xb;
    // stage: chunk c covers B rows {n0+2c, n0+2c+1}, k in [h*256, h*256+256)
    for (int c = wave; c < 32; c += 4) {
      const short* src = Bb + (n0 + 2 * c + (lane >> 5)) * 512 + h * 256 + (lane & 31) * 8;
      __builtin_amdgcn_global_load_lds(
          (const __attribute__((address_space(1))) unsigned int*)src,
          (__attribute__((address_space(3))) unsigned int*)(&Bs[c * 520]),
          16, 0, 0);
    }
    __syncthreads();
    #pragma unroll
    for (int kk = 0; kk < 256; kk += 32) {
      short8 a0 = *(const short8*)(Asrc + ar0 * DD + kk + lkb);
      short8 a1 = *(const short8*)(Asrc + ar1 * DD + kk + lkb);
      short8 b0 = *(const short8*)(&Bs[bb0 + kk]);
      short8 b1 = *(const short8*)(&Bs[bb1 + kk]);
      acc[0][0] = __builtin_amdgcn_mfma_f32_16x16x32_bf16(a0, b0, acc[0][0], 0, 0, 0);
      acc[0][1] = __builtin_amdgcn_mfma_f32_16x16x32_bf16(a0, b1, acc[0][1], 0, 0, 0);
      acc[1][0] = __builtin_amdgcn_mfma_f32_16x16x32_bf16(a1, b0, acc[1][0], 0, 0, 0);
      acc[1][1] = __builtin_amdgcn_mfma_f32_16x16x32_bf16(a1, b1, acc[1][1], 0, 0, 0);
    }
    __syncthreads();
  }

  // D layout: col = lane&15, row = (lane>>4)*4 + reg  [verified m89/m91]
  const int rb = (lane >> 4) * 4, cb = lane & 15;
  #pragma unroll
  for (int i = 0; i < 2; i++) {
    #pragma unroll
    for (int r = 0; r < 4; r++) {
      int gm = m0 + wr + i * 16 + rb + r;
      if (gm < N_NODES) {
        int go = gm * DD + n0 + wc + cb;
        out[go]      = fmaxf(acc[i][0][r], 0.f);
        out[go + 16] = fmaxf(acc[i][1][r], 0.f);
      }
    }
  }
}

extern "C" void kernel_launch(void* const* d_in, const int* in_sizes, int n_in,
                              void* d_out, int out_size, void* d_ws, size_t ws_size,
                              hipStream_t stream) {
  const float* x = (const float*)d_in[0];
  const float* W = (const float*)d_in[1];
  const float* M = (const float*)d_in[2];
  const int* esrc = (const int*)d_in[3];
  const int* edst = (const int*)d_in[4];
  float* out = (float*)d_out;

  char* w = (char*)d_ws;
  short* xb  = (short*)w;                   // 10000*256*2 = 5,120,000 B
  short* axb = (short*)(w + 5120000);       // 10000*256*2 = 5,120,000 B
  short* Bb  = (short*)(w + 10240000);      // 256*512*2   =   262,144 B
  int* deg      = (int*)(w + 10502144);
  int* rowstart = deg + N_NODES;
  int* cursor   = rowstart + N_NODES;
  int* srcs     = cursor + N_NODES;         // 320000 * 4 B

  hipMemsetAsync(deg, 0, N_NODES * sizeof(int), stream);
  k_pre<<<4006, 256, 0, stream>>>(x, W, M, edst, xb, Bb, deg);
  k_scan<<<1, 1024, 0, stream>>>(deg, rowstart, cursor);
  k_scatter<<<1250, 256, 0, stream>>>(esrc, edst, cursor, srcs);
  k_agg<<<2500, 256, 0, stream>>>(xb, rowstart, deg, srcs, axb);
  k_gemm<<<dim3(157, 4), 256, 0, stream>>>(xb, axb, Bb, out);
}